// Round 4
// baseline (234.660 us; speedup 1.0000x reference)
//
#include <hip/hip_runtime.h>

// Problem constants: B=4, h=w=z=16 -> N=4096, C=128, Cq=16
#define NB     4
#define NN     4096
#define NC     128
#define NCQ    16
#define NROWS  (NB * NN)      // 16384
#define NSLICE 4
#define NIT    (NN / 64 / NSLICE)   // 16 iterations of 64 keys per slice

typedef __attribute__((ext_vector_type(8)))  __bf16 bf16x8;
typedef __attribute__((ext_vector_type(4)))  float  f32x4;
typedef __attribute__((ext_vector_type(16))) float  f32x16;

#define MFMA16(a,b,c) __builtin_amdgcn_mfma_f32_16x16x32_bf16((a),(b),(c),0,0,0)
#define MFMA32(a,b,c) __builtin_amdgcn_mfma_f32_32x32x16_bf16((a),(b),(c),0,0,0)
#define LOG2E 1.44269504f
// Schraudolph bias for direct-to-bf16 exp2: bits(bf16(2^s)) ~= 128*s + 16248.66
#define SCH_BIAS 16248.66f

__device__ __forceinline__ f32x16 zero16() {
    f32x16 v;
    #pragma unroll
    for (int i = 0; i < 16; ++i) v[i] = 0.f;
    return v;
}

// Swizzled fragment layouts (lane = lh*32 + l31):
//  qswz: [batch][qb32][lane][8]  elem j = (LOG2E * Q)[32*qb32 + l31][ch = 8*lh + j]
//  kswz: [batch][kb32][lane][8]  elem j = K[32*kb32 + l31][ch = 8*lh + j]
//  vswz: [batch][kb16][cg][lane][8]
//        elem j = V^T[ch = 32*cg + l31][key = 16*kb16 + 4*lh + (j&3) + 8*(j>>2)]
//  Wp:   [oc][ch] bf16, oc 0..15 = Wb cols, 16..31 = Wc cols, 32..159 = Wd cols

// ---------------------------------------------------------------------------
// Kernel 0: one-shot W transpose+convert -> bf16 Wp[160][128].
// ---------------------------------------------------------------------------
__global__ __launch_bounds__(256) void wpre_kernel(
    const float* __restrict__ Wb, const float* __restrict__ Wc,
    const float* __restrict__ Wd, __bf16* __restrict__ Wp)
{
    int idx = blockIdx.x * 256 + threadIdx.x;   // 160*128 = 20480 exactly
    int oc = idx >> 7, ch = idx & 127;
    float v;
    if (oc < 16)      v = Wb[ch * 16 + oc];
    else if (oc < 32) v = Wc[ch * 16 + (oc - 16)];
    else              v = Wd[ch * 128 + (oc - 32)];
    Wp[idx] = (__bf16)v;
}

// ---------------------------------------------------------------------------
// Kernel 1: projections via MFMA; W^T fragments straight from L2-resident Wp
// (prefetched one oc_t ahead). Unchanged from R2 (passed).
// ---------------------------------------------------------------------------
__global__ __launch_bounds__(256) void proj_kernel(
    const float* __restrict__ x,  const __bf16* __restrict__ Wp,
    __bf16* __restrict__ qswz, __bf16* __restrict__ kswz,
    __bf16* __restrict__ vswz)
{
    __shared__ __align__(16) __bf16 xsh[32 * 136];   // [row][136]
    __shared__ __align__(16) float  osb[4][16 * 17]; // per-wave transpose buffer

    const int  t    = threadIdx.x;
    const int  lane = t & 63, w = t >> 6;
    const int  q16  = lane & 15, quad = lane >> 4;
    const long row0 = (long)blockIdx.x * 32;
    const int  batch = (int)(row0 >> 12);
    const int  nloc  = (int)(row0 & 4095);
    const int  rh   = w & 1;
    const int  og   = (w >> 1) * 5;

    #pragma unroll
    for (int i = 0; i < 4; ++i) {
        int idx = t + 256 * i;           // < 1024
        int r = idx >> 5, c4 = (idx & 31) * 4;
        float4 xv = *(const float4*)&x[(row0 + r) * NC + c4];
        union { __bf16 h[4]; uint2 u; } cv;
        cv.h[0] = (__bf16)xv.x; cv.h[1] = (__bf16)xv.y;
        cv.h[2] = (__bf16)xv.z; cv.h[3] = (__bf16)xv.w;
        *(uint2*)&xsh[r * 136 + c4] = cv.u;
    }
    __syncthreads();

    bf16x8 xf[4];
    #pragma unroll
    for (int kc = 0; kc < 4; ++kc)
        xf[kc] = *(const bf16x8*)&xsh[(rh * 16 + q16) * 136 + kc * 32 + quad * 8];

    const __bf16* wbase = Wp + (size_t)(og * 16 + q16) * 128 + quad * 8;
    bf16x8 wfb[4];
    #pragma unroll
    for (int kc = 0; kc < 4; ++kc)
        wfb[kc] = *(const bf16x8*)(wbase + kc * 32);

    float* osw = osb[w];
    #pragma unroll
    for (int oc_t = 0; oc_t < 5; ++oc_t) {
        const int oset = og + oc_t;
        bf16x8 wfc[4];
        #pragma unroll
        for (int kc = 0; kc < 4; ++kc) wfc[kc] = wfb[kc];
        if (oc_t < 4) {                  // prefetch next oc_t's fragments
            const __bf16* wn = wbase + (size_t)(oc_t + 1) * 2048;
            #pragma unroll
            for (int kc = 0; kc < 4; ++kc)
                wfb[kc] = *(const bf16x8*)(wn + kc * 32);
        }
        f32x4 acc = {0.f, 0.f, 0.f, 0.f};
        #pragma unroll
        for (int kc = 0; kc < 4; ++kc)
            acc = MFMA16(wfc[kc], xf[kc], acc);   // D'[oc][row]
        #pragma unroll
        for (int r = 0; r < 4; ++r)
            osw[(quad * 4 + r) * 17 + q16] = acc[r];   // osb[oc16][xrow16]

        if (oset >= 2) {
            int ch_l = lane & 15, lh_t = (lane >> 4) & 1, jh = lane >> 5;
            union { __bf16 h[4]; uint2 u; } cv;
            #pragma unroll
            for (int u2 = 0; u2 < 4; ++u2)
                cv.h[u2] = (__bf16)osw[ch_l * 17 + 8 * jh + 4 * lh_t + u2];
            int kb16 = (nloc >> 4) + rh;
            int cg   = (oset - 2) >> 1;
            int l31v = ((oset - 2) & 1) * 16 + ch_l;
            size_t off = ((((size_t)batch * 256 + kb16) * 4 + cg) << 9)
                       + (size_t)(lh_t * 32 + l31v) * 8 + jh * 4;
            *(uint2*)&vswz[off] = cv.u;
        } else if (lane < 32) {
            int xr = lane & 15, lh_t = lane >> 4;
            const float qsc = (oset == 0) ? LOG2E : 1.f;  // fold log2e into Q
            union { __bf16 h[8]; uint4 u; } cv;
            #pragma unroll
            for (int j = 0; j < 8; ++j)
                cv.h[j] = (__bf16)(osw[(8 * lh_t + j) * 17 + xr] * qsc);
            size_t off = ((((size_t)batch * 128 + (nloc >> 5)) * 64)
                       + (size_t)(lh_t * 32 + rh * 16 + xr)) * 8;
            __bf16* dst = (oset == 0) ? qswz : kswz;
            *(uint4*)&dst[off] = cv.u;
        }
    }
}

// ---------------------------------------------------------------------------
// Kernel 2: flash attention — EXACT R2 structure (53.8 us, clean counters:
// WRITE_SIZE == program bytes, no spill), with only evidence-backed deltas:
//   * Ol ones-MFMA removed (-16 AGPR): l accumulated on VALU from the same
//     bf16 P bit patterns (bitcast(e<<16)); lane (l31,lh) covers 32 of each
//     body's 64 keys, partner lane l31^32 the complement -> shfl_xor(32).
//     S is h-independent, so h==0 waves own the l output.
//   * NSLICE 8->4: halves Opart traffic; grid 1024 = exactly 4 blocks/CU.
//   * NO unroll pragma on the it-loop (R3's full unroll under the (256,4)
//     128-reg cap caused scratch spill: 142 MB HBM writes. This is the A/B.)
// Double-buffered va/vb and scatter 2-B stores kept verbatim from R2.
// ---------------------------------------------------------------------------
__global__ __launch_bounds__(256, 4) void attn_kernel(
    const __bf16* __restrict__ qswz, const __bf16* __restrict__ kswz,
    const __bf16* __restrict__ vswz, __bf16* __restrict__ Opart,
    float* __restrict__ lws)
{
    const int t    = threadIdx.x;
    const int lane = t & 63, w = t >> 6;
    const int l31 = lane & 31, lh = lane >> 5;
    const int bid   = blockIdx.x;
    const int xcd   = bid & 7;
    const int batch = xcd >> 1;              // constant per XCD
    const int spL   = xcd & 1;               // slice bit0, constant per XCD
    const int idx   = bid >> 3;              // 0..127
    const int qpair = idx & 63;              // 0..63
    const int spH   = idx >> 6;              // 0..1
    const int slice = (spH << 1) | spL;      // 0..3 (block-uniform)
    const int qb32  = qpair * 2 + (w >> 1);  // waves pair on q
    const int h     = w & 1;                 // channel half
    const int ks0   = slice * (64 * NIT);

    // Q B-frag, fixed: n = q = 32*qb32 + l31, k = ch = 8*lh + j
    const bf16x8 qf = *(const bf16x8*)
        &qswz[(((size_t)batch * 128 + qb32) * 64 + lane) * 8];

    const __bf16* kptr = kswz + ((size_t)batch * 128 + (ks0 >> 5)) * 512 + lane * 8;
    const __bf16* vptr = vswz + ((size_t)batch * 256 + (ks0 >> 4)) * 2048
                       + h * 1024 + lane * 8;

    f32x16 O0 = zero16(), O1 = zero16();
    float  lacc = 0.f;
    const bool do_l = (h == 0);              // wave-uniform

    bf16x8 kf0 = *(const bf16x8*)(kptr);
    bf16x8 kf1 = *(const bf16x8*)(kptr + 512);
    bf16x8 va[8], vb[8];
    #pragma unroll
    for (int b = 0; b < 4; ++b) {           // iter-0 V frags (ct = 0,1)
        va[2*b]     = *(const bf16x8*)(vptr + (size_t)(b * 4)     * 512);
        va[2*b + 1] = *(const bf16x8*)(vptr + (size_t)(b * 4 + 1) * 512);
    }
    f32x16 S0 = MFMA32(kf0, qf, zero16());
    f32x16 S1 = MFMA32(kf1, qf, zero16());

#define ATTN_BODY(IT, CUR, NXT)                                               \
    {                                                                         \
        const int itn = ((IT) + 1 < NIT) ? (IT) + 1 : (IT);                   \
        kf0 = *(const bf16x8*)(kptr + (size_t)itn * 1024);                    \
        kf1 = *(const bf16x8*)(kptr + (size_t)itn * 1024 + 512);              \
        _Pragma("unroll")                                                     \
        for (int b = 0; b < 4; ++b) {                                         \
            NXT[2*b]     = *(const bf16x8*)(vptr + (size_t)((itn*4+b)*4)*512);\
            NXT[2*b + 1] = *(const bf16x8*)(vptr + (size_t)((itn*4+b)*4+1)*512);\
        }                                                                     \
        union { uint32_t u32[16]; bf16x8 f[4]; } pk;                          \
        _Pragma("unroll")                                                     \
        for (int i = 0; i < 8; ++i) {                                         \
            int e0 = (int)fmaf(S0[2*i],   128.f, SCH_BIAS);                   \
            int e1 = (int)fmaf(S0[2*i+1], 128.f, SCH_BIAS);                   \
            int e2 = (int)fmaf(S1[2*i],   128.f, SCH_BIAS);                   \
            int e3 = (int)fmaf(S1[2*i+1], 128.f, SCH_BIAS);                   \
            pk.u32[i]     = (uint32_t)((e1 << 16) | e0);                      \
            pk.u32[8 + i] = (uint32_t)((e3 << 16) | e2);                      \
            if (do_l) {                                                       \
                union { uint32_t u; float fv; } c0, c1, c2, c3;               \
                c0.u = (uint32_t)e0 << 16; c1.u = (uint32_t)e1 << 16;         \
                c2.u = (uint32_t)e2 << 16; c3.u = (uint32_t)e3 << 16;         \
                lacc += (c0.fv + c1.fv) + (c2.fv + c3.fv);                    \
            }                                                                 \
        }                                                                     \
        _Pragma("unroll")                                                     \
        for (int b = 0; b < 4; ++b) {                                         \
            O0 = MFMA32(pk.f[b], CUR[2*b],     O0);                           \
            O1 = MFMA32(pk.f[b], CUR[2*b + 1], O1);                           \
        }                                                                     \
        S0 = MFMA32(kf0, qf, zero16());                                       \
        S1 = MFMA32(kf1, qf, zero16());                                       \
    }

    for (int it = 0; it < NIT; it += 2) {
        ATTN_BODY(it,     va, vb);
        ATTN_BODY(it + 1, vb, va);
    }
#undef ATTN_BODY

    const long base = (long)batch * NN;

    // ---- l: lane sum covers this lane's 32 keys/body; partner lane (same
    //      l31, other lh) holds the complement. q = qb32*32 + l31.
    float lfull = lacc + __shfl_xor(lacc, 32);
    if (h == 0 && lh == 0)
        lws[(size_t)slice * NROWS + base + qb32 * 32 + l31] = lfull;

    // ---- O partial -> Opart[slice][row][ch] bf16 (col = ch = 64h+32ct+l31) --
    #pragma unroll
    for (int ct = 0; ct < 2; ++ct) {
        f32x16 Ov = ct ? O1 : O0;
        #pragma unroll
        for (int r = 0; r < 16; ++r) {
            int q = qb32 * 32 + (r & 3) + 8 * (r >> 2) + 4 * lh;
            Opart[((size_t)slice * NROWS + base + q) * NC + 64 * h + 32 * ct + l31]
                = (__bf16)Ov[r];
        }
    }
}

// ---------------------------------------------------------------------------
// Kernel 3: combine 4 slice partials + epilogue: out = gamma*(SumO/Suml)+x.
// ---------------------------------------------------------------------------
__global__ __launch_bounds__(256) void combine_kernel(
    const __bf16* __restrict__ Op, const float* __restrict__ lws,
    const float* __restrict__ x, const float* __restrict__ gamma,
    float* __restrict__ out)
{
    __shared__ float gl[32];
    const int  t    = threadIdx.x;
    const long row0 = (long)blockIdx.x * 32;
    if (t < 32) {
        float l = 0.f;
        #pragma unroll
        for (int s = 0; s < NSLICE; ++s) l += lws[(size_t)s * NROWS + row0 + t];
        gl[t] = gamma[0] / l;
    }
    __syncthreads();
    const size_t s1 = (size_t)NROWS * NC;
    #pragma unroll
    for (int i = 0; i < 2; ++i) {
        int idx = t + 256 * i;                 // < 512 uint4 groups
        int r = idx >> 4, c8 = (idx & 15) * 8;
        size_t g = (size_t)(row0 + r) * NC + c8;
        float a[8];
        #pragma unroll
        for (int j = 0; j < 8; ++j) a[j] = 0.f;
        #pragma unroll
        for (int s = 0; s < NSLICE; ++s) {
            union { __bf16 h[8]; uint4 u; } av;
            av.u = *(const uint4*)&Op[s1 * s + g];
            #pragma unroll
            for (int j = 0; j < 8; ++j) a[j] += (float)av.h[j];
        }
        float sc = gl[r];
        float4 x0 = *(const float4*)&x[g];
        float4 x1 = *(const float4*)&x[g + 4];
        float4 o0, o1;
        o0.x = a[0] * sc + x0.x; o0.y = a[1] * sc + x0.y;
        o0.z = a[2] * sc + x0.z; o0.w = a[3] * sc + x0.w;
        o1.x = a[4] * sc + x1.x; o1.y = a[5] * sc + x1.y;
        o1.z = a[6] * sc + x1.z; o1.w = a[7] * sc + x1.w;
        *(float4*)&out[g]     = o0;
        *(float4*)&out[g + 4] = o1;
    }
}

// ---------------------------------------------------------------------------
extern "C" void kernel_launch(void* const* d_in, const int* in_sizes, int n_in,
                              void* d_out, int out_size, void* d_ws, size_t ws_size,
                              hipStream_t stream) {
    const float* x     = (const float*)d_in[0];
    const float* Wb    = (const float*)d_in[1];
    const float* Wc    = (const float*)d_in[2];
    const float* Wd    = (const float*)d_in[3];
    const float* gamma = (const float*)d_in[4];
    float*       out   = (float*)d_out;

    // ws: qswz .5M | kswz .5M | vswz 4M | Opart 4x4M bf16 | lws 256K | Wp 40K
    __bf16* qswz  = (__bf16*)d_ws;
    __bf16* kswz  = qswz + (size_t)NROWS * NCQ;
    __bf16* vswz  = kswz + (size_t)NROWS * NCQ;
    __bf16* Opart = vswz + (size_t)NB * NC * NN;
    float*  lws   = (float*)(Opart + (size_t)NSLICE * NROWS * NC);
    __bf16* Wp    = (__bf16*)(lws + (size_t)NSLICE * NROWS);

    wpre_kernel   <<<80, 256, 0, stream>>>(Wb, Wc, Wd, Wp);
    proj_kernel   <<<NROWS / 32, 256, 0, stream>>>(x, Wp, qswz, kswz, vswz);
    attn_kernel   <<<NB * 64 * NSLICE, 256, 0, stream>>>(qswz, kswz, vswz, Opart, lws);
    combine_kernel<<<NROWS / 32, 256, 0, stream>>>(Opart, lws, x, gamma, out);
}

// Round 5
// 129.825 us; speedup vs baseline: 1.8075x; 1.8075x over previous
//
#include <hip/hip_runtime.h>

// Problem constants: B=4, h=w=z=16 -> N=4096, C=128, Cq=16
#define NB     4
#define NN     4096
#define NC     128
#define NCQ    16
#define NROWS  (NB * NN)      // 16384
#define NSLICE 8
#define NIT    (NN / 64 / NSLICE)   // 8 iterations of 64 keys per slice

typedef __attribute__((ext_vector_type(8)))  __bf16 bf16x8;
typedef __attribute__((ext_vector_type(4)))  float  f32x4;
typedef __attribute__((ext_vector_type(16))) float  f32x16;

#define MFMA16(a,b,c) __builtin_amdgcn_mfma_f32_16x16x32_bf16((a),(b),(c),0,0,0)
#define MFMA32(a,b,c) __builtin_amdgcn_mfma_f32_32x32x16_bf16((a),(b),(c),0,0,0)
#define LOG2E 1.44269504f
// Schraudolph bias for direct-to-bf16 exp2: bits(bf16(2^s)) ~= 128*s + 16248.66
#define SCH_BIAS 16248.66f

__device__ __forceinline__ f32x16 zero16() {
    f32x16 v;
    #pragma unroll
    for (int i = 0; i < 16; ++i) v[i] = 0.f;
    return v;
}

// Swizzled fragment layouts (lane = lh*32 + l31):
//  qswz: [batch][qb32][lane][8]  elem j = (LOG2E * Q)[32*qb32 + l31][ch = 8*lh + j]
//  kswz: [batch][kb32][lane][8]  elem j = K[32*kb32 + l31][ch = 8*lh + j]
//  vswz: [batch][kb16][cg][lane][8]
//        elem j = V^T[ch = 32*cg + l31][key = 16*kb16 + 4*lh + (j&3) + 8*(j>>2)]
//  Wp:   [oc][ch] bf16, oc 0..15 = Wb cols, 16..31 = Wc cols, 32..159 = Wd cols

// ---------------------------------------------------------------------------
// Kernel 0: one-shot W transpose+convert -> bf16 Wp[160][128].
// ---------------------------------------------------------------------------
__global__ __launch_bounds__(256) void wpre_kernel(
    const float* __restrict__ Wb, const float* __restrict__ Wc,
    const float* __restrict__ Wd, __bf16* __restrict__ Wp)
{
    int idx = blockIdx.x * 256 + threadIdx.x;   // 160*128 = 20480 exactly
    int oc = idx >> 7, ch = idx & 127;
    float v;
    if (oc < 16)      v = Wb[ch * 16 + oc];
    else if (oc < 32) v = Wc[ch * 16 + (oc - 16)];
    else              v = Wd[ch * 128 + (oc - 32)];
    Wp[idx] = (__bf16)v;
}

// ---------------------------------------------------------------------------
// Kernel 1: projections via MFMA; W^T fragments straight from L2-resident Wp
// (prefetched one oc_t ahead). R2-verified structure; this round's deltas:
//   * acc chain split 4-deep -> 2x 2-deep (proj is latency-bound at 2
//     waves/SIMD; halves the serial MFMA dependency per oc_t)
//   * per-wave osb alternates between two buffers across oc_t (breaks the
//     LDS WAR serialization between consecutive oc_t iterations)
// ---------------------------------------------------------------------------
__global__ __launch_bounds__(256) void proj_kernel(
    const float* __restrict__ x,  const __bf16* __restrict__ Wp,
    __bf16* __restrict__ qswz, __bf16* __restrict__ kswz,
    __bf16* __restrict__ vswz)
{
    __shared__ __align__(16) __bf16 xsh[32 * 136];   // [row][136]
    __shared__ __align__(16) float  osb[8][16 * 17]; // 2 per wave, alternating

    const int  t    = threadIdx.x;
    const int  lane = t & 63, w = t >> 6;
    const int  q16  = lane & 15, quad = lane >> 4;
    const long row0 = (long)blockIdx.x * 32;
    const int  batch = (int)(row0 >> 12);
    const int  nloc  = (int)(row0 & 4095);
    const int  rh   = w & 1;
    const int  og   = (w >> 1) * 5;

    #pragma unroll
    for (int i = 0; i < 4; ++i) {
        int idx = t + 256 * i;           // < 1024
        int r = idx >> 5, c4 = (idx & 31) * 4;
        float4 xv = *(const float4*)&x[(row0 + r) * NC + c4];
        union { __bf16 h[4]; uint2 u; } cv;
        cv.h[0] = (__bf16)xv.x; cv.h[1] = (__bf16)xv.y;
        cv.h[2] = (__bf16)xv.z; cv.h[3] = (__bf16)xv.w;
        *(uint2*)&xsh[r * 136 + c4] = cv.u;
    }
    __syncthreads();

    bf16x8 xf[4];
    #pragma unroll
    for (int kc = 0; kc < 4; ++kc)
        xf[kc] = *(const bf16x8*)&xsh[(rh * 16 + q16) * 136 + kc * 32 + quad * 8];

    const __bf16* wbase = Wp + (size_t)(og * 16 + q16) * 128 + quad * 8;
    bf16x8 wfb[4];
    #pragma unroll
    for (int kc = 0; kc < 4; ++kc)
        wfb[kc] = *(const bf16x8*)(wbase + kc * 32);

    #pragma unroll
    for (int oc_t = 0; oc_t < 5; ++oc_t) {
        const int oset = og + oc_t;
        bf16x8 wfc[4];
        #pragma unroll
        for (int kc = 0; kc < 4; ++kc) wfc[kc] = wfb[kc];
        if (oc_t < 4) {                  // prefetch next oc_t's fragments
            const __bf16* wn = wbase + (size_t)(oc_t + 1) * 2048;
            #pragma unroll
            for (int kc = 0; kc < 4; ++kc)
                wfb[kc] = *(const bf16x8*)(wn + kc * 32);
        }
        f32x4 acc0 = {0.f, 0.f, 0.f, 0.f};
        f32x4 acc1 = {0.f, 0.f, 0.f, 0.f};
        acc0 = MFMA16(wfc[0], xf[0], acc0);   // two independent 2-deep chains
        acc1 = MFMA16(wfc[1], xf[1], acc1);
        acc0 = MFMA16(wfc[2], xf[2], acc0);
        acc1 = MFMA16(wfc[3], xf[3], acc1);
        f32x4 acc = acc0 + acc1;              // D'[oc][row]

        float* osw = osb[w * 2 + (oc_t & 1)];
        #pragma unroll
        for (int r = 0; r < 4; ++r)
            osw[(quad * 4 + r) * 17 + q16] = acc[r];   // osb[oc16][xrow16]

        if (oset >= 2) {
            int ch_l = lane & 15, lh_t = (lane >> 4) & 1, jh = lane >> 5;
            union { __bf16 h[4]; uint2 u; } cv;
            #pragma unroll
            for (int u2 = 0; u2 < 4; ++u2)
                cv.h[u2] = (__bf16)osw[ch_l * 17 + 8 * jh + 4 * lh_t + u2];
            int kb16 = (nloc >> 4) + rh;
            int cg   = (oset - 2) >> 1;
            int l31v = ((oset - 2) & 1) * 16 + ch_l;
            size_t off = ((((size_t)batch * 256 + kb16) * 4 + cg) << 9)
                       + (size_t)(lh_t * 32 + l31v) * 8 + jh * 4;
            *(uint2*)&vswz[off] = cv.u;
        } else if (lane < 32) {
            int xr = lane & 15, lh_t = lane >> 4;
            const float qsc = (oset == 0) ? LOG2E : 1.f;  // fold log2e into Q
            union { __bf16 h[8]; uint4 u; } cv;
            #pragma unroll
            for (int j = 0; j < 8; ++j)
                cv.h[j] = (__bf16)(osw[(8 * lh_t + j) * 17 + xr] * qsc);
            size_t off = ((((size_t)batch * 128 + (nloc >> 5)) * 64)
                       + (size_t)(lh_t * 32 + rh * 16 + xr)) * 8;
            __bf16* dst = (oset == 0) ? qswz : kswz;
            *(uint4*)&dst[off] = cv.u;
        }
    }
}

// ---------------------------------------------------------------------------
// Kernel 2: flash attention — R2 kernel restored VERBATIM (53.8 us, clean:
// WRITE_SIZE == program bytes, no spill). R3/R4 lesson: the R2 config sits
// just under the (256,4) 128-reg cliff; the lacc VALU accumulation and
// NIT=16 each pushed it over (142 MB / 440 MB scratch writes). Do not add
// ANY register pressure inside the K-loop.
// Single delta vs R2, zero live-range cost: the pack (e1<<16)|e0 is now one
// v_perm_b32 instead of shl+or (bit-identical low-16 semantics).
// ---------------------------------------------------------------------------
__global__ __launch_bounds__(256, 4) void attn_kernel(
    const __bf16* __restrict__ qswz, const __bf16* __restrict__ kswz,
    const __bf16* __restrict__ vswz, __bf16* __restrict__ Opart,
    float* __restrict__ lws)
{
    const int t    = threadIdx.x;
    const int lane = t & 63, w = t >> 6;
    const int l31 = lane & 31, lh = lane >> 5;
    const int bid   = blockIdx.x;
    const int xcd   = bid & 7;
    const int batch = xcd >> 1;              // constant per XCD
    const int spL   = xcd & 1;               // slice bit0, constant per XCD
    const int idx   = bid >> 3;              // 0..255
    const int qpair = idx & 63;              // 0..63
    const int spH   = idx >> 6;              // 0..3
    const int slice = (spH << 1) | spL;      // 0..7 (block-uniform)
    const int qb32  = qpair * 2 + (w >> 1);  // waves pair on q
    const int h     = w & 1;                 // channel half
    const int ks0   = slice * (64 * NIT);

    // Q B-frag, fixed: n = q = 32*qb32 + l31, k = ch = 8*lh + j
    const bf16x8 qf = *(const bf16x8*)
        &qswz[(((size_t)batch * 128 + qb32) * 64 + lane) * 8];

    const __bf16* kptr = kswz + ((size_t)batch * 128 + (ks0 >> 5)) * 512 + lane * 8;
    const __bf16* vptr = vswz + ((size_t)batch * 256 + (ks0 >> 4)) * 2048
                       + h * 1024 + lane * 8;

    // ones B-fragment (bf16 1.0 pairs) for the l-summing MFMA
    union { uint32_t u[4]; bf16x8 f; } onesu;
    #pragma unroll
    for (int i = 0; i < 4; ++i) onesu.u[i] = 0x3F803F80u;
    const bf16x8 ones = onesu.f;

    f32x16 O0 = zero16(), O1 = zero16(), Ol = zero16();

    bf16x8 kf0 = *(const bf16x8*)(kptr);
    bf16x8 kf1 = *(const bf16x8*)(kptr + 512);
    bf16x8 va[8], vb[8];
    #pragma unroll
    for (int b = 0; b < 4; ++b) {           // iter-0 V frags (ct = 0,1)
        va[2*b]     = *(const bf16x8*)(vptr + (size_t)(b * 4)     * 512);
        va[2*b + 1] = *(const bf16x8*)(vptr + (size_t)(b * 4 + 1) * 512);
    }
    f32x16 S0 = MFMA32(kf0, qf, zero16());
    f32x16 S1 = MFMA32(kf1, qf, zero16());

#define ATTN_BODY(IT, CUR, NXT)                                               \
    {                                                                         \
        const int itn = ((IT) + 1 < NIT) ? (IT) + 1 : (IT);                   \
        kf0 = *(const bf16x8*)(kptr + (size_t)itn * 1024);                    \
        kf1 = *(const bf16x8*)(kptr + (size_t)itn * 1024 + 512);              \
        _Pragma("unroll")                                                     \
        for (int b = 0; b < 4; ++b) {                                         \
            NXT[2*b]     = *(const bf16x8*)(vptr + (size_t)((itn*4+b)*4)*512);\
            NXT[2*b + 1] = *(const bf16x8*)(vptr + (size_t)((itn*4+b)*4+1)*512);\
        }                                                                     \
        union { uint32_t u32[16]; bf16x8 f[4]; } pk;                          \
        _Pragma("unroll")                                                     \
        for (int i = 0; i < 8; ++i) {                                         \
            int e0 = (int)fmaf(S0[2*i],   128.f, SCH_BIAS);                   \
            int e1 = (int)fmaf(S0[2*i+1], 128.f, SCH_BIAS);                   \
            int e2 = (int)fmaf(S1[2*i],   128.f, SCH_BIAS);                   \
            int e3 = (int)fmaf(S1[2*i+1], 128.f, SCH_BIAS);                   \
            pk.u32[i]     = __builtin_amdgcn_perm((uint32_t)e1,               \
                                                  (uint32_t)e0, 0x05040100u);\
            pk.u32[8 + i] = __builtin_amdgcn_perm((uint32_t)e3,               \
                                                  (uint32_t)e2, 0x05040100u);\
        }                                                                     \
        _Pragma("unroll")                                                     \
        for (int b = 0; b < 4; ++b) {                                         \
            O0 = MFMA32(pk.f[b], CUR[2*b],     O0);                           \
            O1 = MFMA32(pk.f[b], CUR[2*b + 1], O1);                           \
            Ol = MFMA32(pk.f[b], ones,         Ol);                           \
        }                                                                     \
        S0 = MFMA32(kf0, qf, zero16());                                       \
        S1 = MFMA32(kf1, qf, zero16());                                       \
    }

    for (int it = 0; it < NIT; it += 2) {
        ATTN_BODY(it,     va, vb);
        ATTN_BODY(it + 1, vb, va);
    }
#undef ATTN_BODY

    const long base = (long)batch * NN;

    // ---- l: Ol reg r holds sum over ALL this slice's keys for q(r), any col.
    if (h == 0 && l31 == 0) {
        #pragma unroll
        for (int r = 0; r < 16; ++r) {
            int q = qb32 * 32 + (r & 3) + 8 * (r >> 2) + 4 * lh;
            lws[(size_t)slice * NROWS + base + q] = Ol[r];
        }
    }

    // ---- O partial -> Opart[slice][row][ch] bf16 (col = ch = 64h+32ct+l31) --
    #pragma unroll
    for (int ct = 0; ct < 2; ++ct) {
        f32x16 Ov = ct ? O1 : O0;
        #pragma unroll
        for (int r = 0; r < 16; ++r) {
            int q = qb32 * 32 + (r & 3) + 8 * (r >> 2) + 4 * lh;
            Opart[((size_t)slice * NROWS + base + q) * NC + 64 * h + 32 * ct + l31]
                = (__bf16)Ov[r];
        }
    }
}

// ---------------------------------------------------------------------------
// Kernel 3: combine 8 slice partials + epilogue: out = gamma*(SumO/Suml)+x.
// ---------------------------------------------------------------------------
__global__ __launch_bounds__(256) void combine_kernel(
    const __bf16* __restrict__ Op, const float* __restrict__ lws,
    const float* __restrict__ x, const float* __restrict__ gamma,
    float* __restrict__ out)
{
    __shared__ float gl[32];
    const int  t    = threadIdx.x;
    const long row0 = (long)blockIdx.x * 32;
    if (t < 32) {
        float l = 0.f;
        #pragma unroll
        for (int s = 0; s < NSLICE; ++s) l += lws[(size_t)s * NROWS + row0 + t];
        gl[t] = gamma[0] / l;
    }
    __syncthreads();
    const size_t s1 = (size_t)NROWS * NC;
    #pragma unroll
    for (int i = 0; i < 2; ++i) {
        int idx = t + 256 * i;                 // < 512 uint4 groups
        int r = idx >> 4, c8 = (idx & 15) * 8;
        size_t g = (size_t)(row0 + r) * NC + c8;
        float a[8];
        #pragma unroll
        for (int j = 0; j < 8; ++j) a[j] = 0.f;
        #pragma unroll
        for (int s = 0; s < NSLICE; ++s) {
            union { __bf16 h[8]; uint4 u; } av;
            av.u = *(const uint4*)&Op[s1 * s + g];
            #pragma unroll
            for (int j = 0; j < 8; ++j) a[j] += (float)av.h[j];
        }
        float sc = gl[r];
        float4 x0 = *(const float4*)&x[g];
        float4 x1 = *(const float4*)&x[g + 4];
        float4 o0, o1;
        o0.x = a[0] * sc + x0.x; o0.y = a[1] * sc + x0.y;
        o0.z = a[2] * sc + x0.z; o0.w = a[3] * sc + x0.w;
        o1.x = a[4] * sc + x1.x; o1.y = a[5] * sc + x1.y;
        o1.z = a[6] * sc + x1.z; o1.w = a[7] * sc + x1.w;
        *(float4*)&out[g]     = o0;
        *(float4*)&out[g + 4] = o1;
    }
}

// ---------------------------------------------------------------------------
extern "C" void kernel_launch(void* const* d_in, const int* in_sizes, int n_in,
                              void* d_out, int out_size, void* d_ws, size_t ws_size,
                              hipStream_t stream) {
    const float* x     = (const float*)d_in[0];
    const float* Wb    = (const float*)d_in[1];
    const float* Wc    = (const float*)d_in[2];
    const float* Wd    = (const float*)d_in[3];
    const float* gamma = (const float*)d_in[4];
    float*       out   = (float*)d_out;

    // ws: qswz .5M | kswz .5M | vswz 4M | Opart 8x4M bf16 | lws 512K | Wp 40K
    __bf16* qswz  = (__bf16*)d_ws;
    __bf16* kswz  = qswz + (size_t)NROWS * NCQ;
    __bf16* vswz  = kswz + (size_t)NROWS * NCQ;
    __bf16* Opart = vswz + (size_t)NB * NC * NN;
    float*  lws   = (float*)(Opart + (size_t)NSLICE * NROWS * NC);
    __bf16* Wp    = (__bf16*)(lws + (size_t)NSLICE * NROWS);

    wpre_kernel   <<<80, 256, 0, stream>>>(Wb, Wc, Wd, Wp);
    proj_kernel   <<<NROWS / 32, 256, 0, stream>>>(x, Wp, qswz, kswz, vswz);
    attn_kernel   <<<NB * 128 * 4, 256, 0, stream>>>(qswz, kswz, vswz, Opart, lws);
    combine_kernel<<<NROWS / 32, 256, 0, stream>>>(Opart, lws, x, gamma, out);
}

// Round 6
// 117.611 us; speedup vs baseline: 1.9952x; 1.1038x over previous
//
#include <hip/hip_runtime.h>

// Problem constants: B=4, h=w=z=16 -> N=4096, C=128, Cq=16
#define NB     4
#define NN     4096
#define NC     128
#define NCQ    16
#define NROWS  (NB * NN)      // 16384
#define NSLICE 8
#define NBODY  16             // 32-key bodies per slice (512 keys / slice)

typedef __attribute__((ext_vector_type(8)))  __bf16 bf16x8;
typedef __attribute__((ext_vector_type(4)))  float  f32x4;
typedef __attribute__((ext_vector_type(16))) float  f32x16;

#define MFMA16(a,b,c) __builtin_amdgcn_mfma_f32_16x16x32_bf16((a),(b),(c),0,0,0)
#define MFMA32(a,b,c) __builtin_amdgcn_mfma_f32_32x32x16_bf16((a),(b),(c),0,0,0)
#define LOG2E 1.44269504f
// Schraudolph bias for direct-to-bf16 exp2: bits(bf16(2^s)) ~= 128*s + 16248.66
#define SCH_BIAS 16248.66f

__device__ __forceinline__ f32x16 zero16() {
    f32x16 v;
    #pragma unroll
    for (int i = 0; i < 16; ++i) v[i] = 0.f;
    return v;
}

// Swizzled fragment layouts (lane = lh*32 + l31):
//  qswz: [batch][qb32][lane][8]  elem j = (LOG2E * Q)[32*qb32 + l31][ch = 8*lh + j]
//  kswz: [batch][kb32][lane][8]  elem j = K[32*kb32 + l31][ch = 8*lh + j]
//  vswz: [batch][kb16][cg][lane][8]
//        elem j = V^T[ch = 32*cg + l31][key = 16*kb16 + 4*lh + (j&3) + 8*(j>>2)]
//  Wp:   [oc][ch] bf16, oc 0..15 = Wb cols, 16..31 = Wc cols, 32..159 = Wd cols

// ---------------------------------------------------------------------------
// Kernel 0: one-shot W transpose+convert -> bf16 Wp[160][128].
// ---------------------------------------------------------------------------
__global__ __launch_bounds__(256) void wpre_kernel(
    const float* __restrict__ Wb, const float* __restrict__ Wc,
    const float* __restrict__ Wd, __bf16* __restrict__ Wp)
{
    int idx = blockIdx.x * 256 + threadIdx.x;   // 160*128 = 20480 exactly
    int oc = idx >> 7, ch = idx & 127;
    float v;
    if (oc < 16)      v = Wb[ch * 16 + oc];
    else if (oc < 32) v = Wc[ch * 16 + (oc - 16)];
    else              v = Wd[ch * 128 + (oc - 32)];
    Wp[idx] = (__bf16)v;
}

// ---------------------------------------------------------------------------
// Kernel 1: projections via MFMA; W^T fragments straight from L2-resident Wp
// (prefetched one oc_t ahead). Reverted VERBATIM to the R2 version: R5's
// split-acc + alternating-osb tweak cost ~4 us (R5 total == R2 total while
// attn improved 4 us).
// ---------------------------------------------------------------------------
__global__ __launch_bounds__(256) void proj_kernel(
    const float* __restrict__ x,  const __bf16* __restrict__ Wp,
    __bf16* __restrict__ qswz, __bf16* __restrict__ kswz,
    __bf16* __restrict__ vswz)
{
    __shared__ __align__(16) __bf16 xsh[32 * 136];   // [row][136]
    __shared__ __align__(16) float  osb[4][16 * 17]; // per-wave transpose buffer

    const int  t    = threadIdx.x;
    const int  lane = t & 63, w = t >> 6;
    const int  q16  = lane & 15, quad = lane >> 4;
    const long row0 = (long)blockIdx.x * 32;
    const int  batch = (int)(row0 >> 12);
    const int  nloc  = (int)(row0 & 4095);
    const int  rh   = w & 1;
    const int  og   = (w >> 1) * 5;

    #pragma unroll
    for (int i = 0; i < 4; ++i) {
        int idx = t + 256 * i;           // < 1024
        int r = idx >> 5, c4 = (idx & 31) * 4;
        float4 xv = *(const float4*)&x[(row0 + r) * NC + c4];
        union { __bf16 h[4]; uint2 u; } cv;
        cv.h[0] = (__bf16)xv.x; cv.h[1] = (__bf16)xv.y;
        cv.h[2] = (__bf16)xv.z; cv.h[3] = (__bf16)xv.w;
        *(uint2*)&xsh[r * 136 + c4] = cv.u;
    }
    __syncthreads();

    bf16x8 xf[4];
    #pragma unroll
    for (int kc = 0; kc < 4; ++kc)
        xf[kc] = *(const bf16x8*)&xsh[(rh * 16 + q16) * 136 + kc * 32 + quad * 8];

    const __bf16* wbase = Wp + (size_t)(og * 16 + q16) * 128 + quad * 8;
    bf16x8 wfb[4];
    #pragma unroll
    for (int kc = 0; kc < 4; ++kc)
        wfb[kc] = *(const bf16x8*)(wbase + kc * 32);

    float* osw = osb[w];
    #pragma unroll
    for (int oc_t = 0; oc_t < 5; ++oc_t) {
        const int oset = og + oc_t;
        bf16x8 wfc[4];
        #pragma unroll
        for (int kc = 0; kc < 4; ++kc) wfc[kc] = wfb[kc];
        if (oc_t < 4) {                  // prefetch next oc_t's fragments
            const __bf16* wn = wbase + (size_t)(oc_t + 1) * 2048;
            #pragma unroll
            for (int kc = 0; kc < 4; ++kc)
                wfb[kc] = *(const bf16x8*)(wn + kc * 32);
        }
        f32x4 acc = {0.f, 0.f, 0.f, 0.f};
        #pragma unroll
        for (int kc = 0; kc < 4; ++kc)
            acc = MFMA16(wfc[kc], xf[kc], acc);   // D'[oc][row]
        #pragma unroll
        for (int r = 0; r < 4; ++r)
            osw[(quad * 4 + r) * 17 + q16] = acc[r];   // osb[oc16][xrow16]

        if (oset >= 2) {
            int ch_l = lane & 15, lh_t = (lane >> 4) & 1, jh = lane >> 5;
            union { __bf16 h[4]; uint2 u; } cv;
            #pragma unroll
            for (int u2 = 0; u2 < 4; ++u2)
                cv.h[u2] = (__bf16)osw[ch_l * 17 + 8 * jh + 4 * lh_t + u2];
            int kb16 = (nloc >> 4) + rh;
            int cg   = (oset - 2) >> 1;
            int l31v = ((oset - 2) & 1) * 16 + ch_l;
            size_t off = ((((size_t)batch * 256 + kb16) * 4 + cg) << 9)
                       + (size_t)(lh_t * 32 + l31v) * 8 + jh * 4;
            *(uint2*)&vswz[off] = cv.u;
        } else if (lane < 32) {
            int xr = lane & 15, lh_t = lane >> 4;
            const float qsc = (oset == 0) ? LOG2E : 1.f;  // fold log2e into Q
            union { __bf16 h[8]; uint4 u; } cv;
            #pragma unroll
            for (int j = 0; j < 8; ++j)
                cv.h[j] = (__bf16)(osw[(8 * lh_t + j) * 17 + xr] * qsc);
            size_t off = ((((size_t)batch * 128 + (nloc >> 5)) * 64)
                       + (size_t)(lh_t * 32 + rh * 16 + xr)) * 8;
            __bf16* dst = (oset == 0) ? qswz : kswz;
            *(uint4*)&dst[off] = cv.u;
        }
    }
}

// ---------------------------------------------------------------------------
// Kernel 2: flash attention — 32-key bodies for occupancy. R5 counters:
// Occ 35.8% = 3 waves/SIMD, both pipes <24% -> latency-bound on registers
// (va[8]+vb[8]=64 VGPR + 80 AGPR ~ 160 regs). This version halves the body:
//   * one S f32x16 instead of S0/S1            (-16 AGPR)
//   * V double-buffer va[4]/vb[4] not [8]/[8]  (-32 VGPR)
//   * Ol ones-MFMA replaced by lacc VALU sum (correctness proven R3/R4;
//     now affordable with the halved live set)  (-16 AGPR)
// Budget ~48 AGPR + ~62 VGPR ~= 110 -> 4 waves/SIMD under the (256,4) cap
// with margin. Same keys/loads, same proven 2-body rotation, same perm pack
// (R5-verified), same scatter epilogue (WRITE_SIZE == program bytes).
// Spill gate: attn WRITE_SIZE > 40 MB next round => revert to R5 attn.
// ---------------------------------------------------------------------------
__global__ __launch_bounds__(256, 4) void attn_kernel(
    const __bf16* __restrict__ qswz, const __bf16* __restrict__ kswz,
    const __bf16* __restrict__ vswz, __bf16* __restrict__ Opart,
    float* __restrict__ lws)
{
    const int t    = threadIdx.x;
    const int lane = t & 63, w = t >> 6;
    const int l31 = lane & 31, lh = lane >> 5;
    const int bid   = blockIdx.x;
    const int xcd   = bid & 7;
    const int batch = xcd >> 1;              // constant per XCD
    const int spL   = xcd & 1;               // slice bit0, constant per XCD
    const int idx   = bid >> 3;              // 0..255
    const int qpair = idx & 63;              // 0..63
    const int spH   = idx >> 6;              // 0..3
    const int slice = (spH << 1) | spL;      // 0..7 (block-uniform)
    const int qb32  = qpair * 2 + (w >> 1);  // waves pair on q
    const int h     = w & 1;                 // channel half
    const int ks0   = slice * 512;           // first key of this slice

    // Q B-frag, fixed: n = q = 32*qb32 + l31, k = ch = 8*lh + j
    const bf16x8 qf = *(const bf16x8*)
        &qswz[(((size_t)batch * 128 + qb32) * 64 + lane) * 8];

    const __bf16* kptr = kswz + ((size_t)batch * 128 + (ks0 >> 5)) * 512 + lane * 8;
    const __bf16* vptr = vswz + ((size_t)batch * 256 + (ks0 >> 4)) * 2048
                       + h * 1024 + lane * 8;

    f32x16 O0 = zero16(), O1 = zero16();
    float  lacc = 0.f;
    const bool do_l = (h == 0);              // wave-uniform

    // prologue: body 0 K and V, then its scores
    bf16x8 kf = *(const bf16x8*)(kptr);
    bf16x8 va[4], vb[4];
    #pragma unroll
    for (int s = 0; s < 2; ++s) {            // body 0: kb16 = s, cg = 2h+ct
        va[2*s]     = *(const bf16x8*)(vptr + (size_t)(s * 4)     * 512);
        va[2*s + 1] = *(const bf16x8*)(vptr + (size_t)(s * 4 + 1) * 512);
    }
    f32x16 S = MFMA32(kf, qf, zero16());

// Body m (32 keys): S holds scores (computed at end of previous body).
// pk.f[0] = keys [32m,32m+16), pk.f[1] = [32m+16,32m+32) — verified against
// vswz key layout: bf16 j of pk.f[s] = S[8s+j] = key 16s+(j&3)+8*(j>>2)+4lh.
#define ATTN_BODY(M, CUR, NXT)                                                \
    {                                                                         \
        const int mn = ((M) + 1 < NBODY) ? (M) + 1 : (M);                     \
        kf = *(const bf16x8*)(kptr + (size_t)mn * 512);                       \
        _Pragma("unroll")                                                     \
        for (int s = 0; s < 2; ++s) {                                         \
            NXT[2*s]     = *(const bf16x8*)(vptr + (size_t)((2*mn+s)*4  )*512);\
            NXT[2*s + 1] = *(const bf16x8*)(vptr + (size_t)((2*mn+s)*4+1)*512);\
        }                                                                     \
        union { uint32_t u32[8]; bf16x8 f[2]; } pk;                           \
        _Pragma("unroll")                                                     \
        for (int i = 0; i < 8; ++i) {                                         \
            int e0 = (int)fmaf(S[2*i],   128.f, SCH_BIAS);                    \
            int e1 = (int)fmaf(S[2*i+1], 128.f, SCH_BIAS);                    \
            pk.u32[i] = __builtin_amdgcn_perm((uint32_t)e1,                   \
                                              (uint32_t)e0, 0x05040100u);     \
            if (do_l) {                                                       \
                union { uint32_t u; float fv; } c0, c1;                       \
                c0.u = (uint32_t)e0 << 16; c1.u = (uint32_t)e1 << 16;         \
                lacc += c0.fv + c1.fv;                                        \
            }                                                                 \
        }                                                                     \
        O0 = MFMA32(pk.f[0], CUR[0], O0);                                     \
        O1 = MFMA32(pk.f[0], CUR[1], O1);                                     \
        O0 = MFMA32(pk.f[1], CUR[2], O0);                                     \
        O1 = MFMA32(pk.f[1], CUR[3], O1);                                     \
        S = MFMA32(kf, qf, zero16());                                         \
    }

    for (int m = 0; m < NBODY; m += 2) {
        ATTN_BODY(m,     va, vb);
        ATTN_BODY(m + 1, vb, va);
    }
#undef ATTN_BODY

    const long base = (long)batch * NN;

    // ---- l: lane (l31,lh) summed 16 of each body's 32 keys for q = l31;
    //      partner lane (same l31, lh^1) holds the complement.
    float lfull = lacc + __shfl_xor(lacc, 32);
    if (h == 0 && lh == 0)
        lws[(size_t)slice * NROWS + base + qb32 * 32 + l31] = lfull;

    // ---- O partial -> Opart[slice][row][ch] bf16 (col = ch = 64h+32ct+l31) --
    #pragma unroll
    for (int ct = 0; ct < 2; ++ct) {
        f32x16 Ov = ct ? O1 : O0;
        #pragma unroll
        for (int r = 0; r < 16; ++r) {
            int q = qb32 * 32 + (r & 3) + 8 * (r >> 2) + 4 * lh;
            Opart[((size_t)slice * NROWS + base + q) * NC + 64 * h + 32 * ct + l31]
                = (__bf16)Ov[r];
        }
    }
}

// ---------------------------------------------------------------------------
// Kernel 3: combine 8 slice partials + epilogue: out = gamma*(SumO/Suml)+x.
// ---------------------------------------------------------------------------
__global__ __launch_bounds__(256) void combine_kernel(
    const __bf16* __restrict__ Op, const float* __restrict__ lws,
    const float* __restrict__ x, const float* __restrict__ gamma,
    float* __restrict__ out)
{
    __shared__ float gl[32];
    const int  t    = threadIdx.x;
    const long row0 = (long)blockIdx.x * 32;
    if (t < 32) {
        float l = 0.f;
        #pragma unroll
        for (int s = 0; s < NSLICE; ++s) l += lws[(size_t)s * NROWS + row0 + t];
        gl[t] = gamma[0] / l;
    }
    __syncthreads();
    const size_t s1 = (size_t)NROWS * NC;
    #pragma unroll
    for (int i = 0; i < 2; ++i) {
        int idx = t + 256 * i;                 // < 512 uint4 groups
        int r = idx >> 4, c8 = (idx & 15) * 8;
        size_t g = (size_t)(row0 + r) * NC + c8;
        float a[8];
        #pragma unroll
        for (int j = 0; j < 8; ++j) a[j] = 0.f;
        #pragma unroll
        for (int s = 0; s < NSLICE; ++s) {
            union { __bf16 h[8]; uint4 u; } av;
            av.u = *(const uint4*)&Op[s1 * s + g];
            #pragma unroll
            for (int j = 0; j < 8; ++j) a[j] += (float)av.h[j];
        }
        float sc = gl[r];
        float4 x0 = *(const float4*)&x[g];
        float4 x1 = *(const float4*)&x[g + 4];
        float4 o0, o1;
        o0.x = a[0] * sc + x0.x; o0.y = a[1] * sc + x0.y;
        o0.z = a[2] * sc + x0.z; o0.w = a[3] * sc + x0.w;
        o1.x = a[4] * sc + x1.x; o1.y = a[5] * sc + x1.y;
        o1.z = a[6] * sc + x1.z; o1.w = a[7] * sc + x1.w;
        *(float4*)&out[g]     = o0;
        *(float4*)&out[g + 4] = o1;
    }
}

// ---------------------------------------------------------------------------
extern "C" void kernel_launch(void* const* d_in, const int* in_sizes, int n_in,
                              void* d_out, int out_size, void* d_ws, size_t ws_size,
                              hipStream_t stream) {
    const float* x     = (const float*)d_in[0];
    const float* Wb    = (const float*)d_in[1];
    const float* Wc    = (const float*)d_in[2];
    const float* Wd    = (const float*)d_in[3];
    const float* gamma = (const float*)d_in[4];
    float*       out   = (float*)d_out;

    // ws: qswz .5M | kswz .5M | vswz 4M | Opart 8x4M bf16 | lws 512K | Wp 40K
    __bf16* qswz  = (__bf16*)d_ws;
    __bf16* kswz  = qswz + (size_t)NROWS * NCQ;
    __bf16* vswz  = kswz + (size_t)NROWS * NCQ;
    __bf16* Opart = vswz + (size_t)NB * NC * NN;
    float*  lws   = (float*)(Opart + (size_t)NSLICE * NROWS * NC);
    __bf16* Wp    = (__bf16*)(lws + (size_t)NSLICE * NROWS);

    wpre_kernel   <<<80, 256, 0, stream>>>(Wb, Wc, Wd, Wp);
    proj_kernel   <<<NROWS / 32, 256, 0, stream>>>(x, Wp, qswz, kswz, vswz);
    attn_kernel   <<<NB * 128 * 4, 256, 0, stream>>>(qswz, kswz, vswz, Opart, lws);
    combine_kernel<<<NROWS / 32, 256, 0, stream>>>(Opart, lws, x, gamma, out);
}

// Round 7
// 112.492 us; speedup vs baseline: 2.0860x; 1.0455x over previous
//
#include <hip/hip_runtime.h>

// Problem constants: B=4, h=w=z=16 -> N=4096, C=128, Cq=16
#define NB     4
#define NN     4096
#define NC     128
#define NCQ    16
#define NROWS  (NB * NN)      // 16384
#define NSLICE 4
#define NBODY  32             // 32-key bodies per slice (1024 keys / slice)

typedef __attribute__((ext_vector_type(8)))  __bf16 bf16x8;
typedef __attribute__((ext_vector_type(4)))  float  f32x4;
typedef __attribute__((ext_vector_type(16))) float  f32x16;

#define MFMA16(a,b,c) __builtin_amdgcn_mfma_f32_16x16x32_bf16((a),(b),(c),0,0,0)
#define MFMA32(a,b,c) __builtin_amdgcn_mfma_f32_32x32x16_bf16((a),(b),(c),0,0,0)
#define LOG2E 1.44269504f
// Schraudolph bias for direct-to-bf16 exp2: bits(bf16(2^s)) ~= 128*s + 16248.66
#define SCH_BIAS 16248.66f

__device__ __forceinline__ f32x16 zero16() {
    f32x16 v;
    #pragma unroll
    for (int i = 0; i < 16; ++i) v[i] = 0.f;
    return v;
}

// Swizzled fragment layouts (lane = lh*32 + l31):
//  qswz: [batch][qb32][lane][8]  elem j = (LOG2E * Q)[32*qb32 + l31][ch = 8*lh + j]
//  kswz: [batch][kb32][lane][8]  elem j = K[32*kb32 + l31][ch = 8*lh + j]
//  vswz: [batch][kb16][cg][lane][8]
//        elem j = V^T[ch = 32*cg + l31][key = 16*kb16 + 4*lh + (j&3) + 8*(j>>2)]
//  Wp:   [oc][ch] bf16, oc 0..15 = Wb cols, 16..31 = Wc cols, 32..159 = Wd cols

// ---------------------------------------------------------------------------
// Kernel 0: one-shot W transpose+convert -> bf16 Wp[160][128].
// ---------------------------------------------------------------------------
__global__ __launch_bounds__(256) void wpre_kernel(
    const float* __restrict__ Wb, const float* __restrict__ Wc,
    const float* __restrict__ Wd, __bf16* __restrict__ Wp)
{
    int idx = blockIdx.x * 256 + threadIdx.x;   // 160*128 = 20480 exactly
    int oc = idx >> 7, ch = idx & 127;
    float v;
    if (oc < 16)      v = Wb[ch * 16 + oc];
    else if (oc < 32) v = Wc[ch * 16 + (oc - 16)];
    else              v = Wd[ch * 128 + (oc - 32)];
    Wp[idx] = (__bf16)v;
}

// ---------------------------------------------------------------------------
// Kernel 1: projections via MFMA; W^T fragments straight from L2-resident Wp
// (prefetched one oc_t ahead). R2-verified version, frozen (R5's ILP tweak
// cost ~4 us and was reverted in R6).
// ---------------------------------------------------------------------------
__global__ __launch_bounds__(256) void proj_kernel(
    const float* __restrict__ x,  const __bf16* __restrict__ Wp,
    __bf16* __restrict__ qswz, __bf16* __restrict__ kswz,
    __bf16* __restrict__ vswz)
{
    __shared__ __align__(16) __bf16 xsh[32 * 136];   // [row][136]
    __shared__ __align__(16) float  osb[4][16 * 17]; // per-wave transpose buffer

    const int  t    = threadIdx.x;
    const int  lane = t & 63, w = t >> 6;
    const int  q16  = lane & 15, quad = lane >> 4;
    const long row0 = (long)blockIdx.x * 32;
    const int  batch = (int)(row0 >> 12);
    const int  nloc  = (int)(row0 & 4095);
    const int  rh   = w & 1;
    const int  og   = (w >> 1) * 5;

    #pragma unroll
    for (int i = 0; i < 4; ++i) {
        int idx = t + 256 * i;           // < 1024
        int r = idx >> 5, c4 = (idx & 31) * 4;
        float4 xv = *(const float4*)&x[(row0 + r) * NC + c4];
        union { __bf16 h[4]; uint2 u; } cv;
        cv.h[0] = (__bf16)xv.x; cv.h[1] = (__bf16)xv.y;
        cv.h[2] = (__bf16)xv.z; cv.h[3] = (__bf16)xv.w;
        *(uint2*)&xsh[r * 136 + c4] = cv.u;
    }
    __syncthreads();

    bf16x8 xf[4];
    #pragma unroll
    for (int kc = 0; kc < 4; ++kc)
        xf[kc] = *(const bf16x8*)&xsh[(rh * 16 + q16) * 136 + kc * 32 + quad * 8];

    const __bf16* wbase = Wp + (size_t)(og * 16 + q16) * 128 + quad * 8;
    bf16x8 wfb[4];
    #pragma unroll
    for (int kc = 0; kc < 4; ++kc)
        wfb[kc] = *(const bf16x8*)(wbase + kc * 32);

    float* osw = osb[w];
    #pragma unroll
    for (int oc_t = 0; oc_t < 5; ++oc_t) {
        const int oset = og + oc_t;
        bf16x8 wfc[4];
        #pragma unroll
        for (int kc = 0; kc < 4; ++kc) wfc[kc] = wfb[kc];
        if (oc_t < 4) {                  // prefetch next oc_t's fragments
            const __bf16* wn = wbase + (size_t)(oc_t + 1) * 2048;
            #pragma unroll
            for (int kc = 0; kc < 4; ++kc)
                wfb[kc] = *(const bf16x8*)(wn + kc * 32);
        }
        f32x4 acc = {0.f, 0.f, 0.f, 0.f};
        #pragma unroll
        for (int kc = 0; kc < 4; ++kc)
            acc = MFMA16(wfc[kc], xf[kc], acc);   // D'[oc][row]
        #pragma unroll
        for (int r = 0; r < 4; ++r)
            osw[(quad * 4 + r) * 17 + q16] = acc[r];   // osb[oc16][xrow16]

        if (oset >= 2) {
            int ch_l = lane & 15, lh_t = (lane >> 4) & 1, jh = lane >> 5;
            union { __bf16 h[4]; uint2 u; } cv;
            #pragma unroll
            for (int u2 = 0; u2 < 4; ++u2)
                cv.h[u2] = (__bf16)osw[ch_l * 17 + 8 * jh + 4 * lh_t + u2];
            int kb16 = (nloc >> 4) + rh;
            int cg   = (oset - 2) >> 1;
            int l31v = ((oset - 2) & 1) * 16 + ch_l;
            size_t off = ((((size_t)batch * 256 + kb16) * 4 + cg) << 9)
                       + (size_t)(lh_t * 32 + l31v) * 8 + jh * 4;
            *(uint2*)&vswz[off] = cv.u;
        } else if (lane < 32) {
            int xr = lane & 15, lh_t = lane >> 4;
            const float qsc = (oset == 0) ? LOG2E : 1.f;  // fold log2e into Q
            union { __bf16 h[8]; uint4 u; } cv;
            #pragma unroll
            for (int j = 0; j < 8; ++j)
                cv.h[j] = (__bf16)(osw[(8 * lh_t + j) * 17 + xr] * qsc);
            size_t off = ((((size_t)batch * 128 + (nloc >> 5)) * 64)
                       + (size_t)(lh_t * 32 + rh * 16 + xr)) * 8;
            __bf16* dst = (oset == 0) ? qswz : kswz;
            *(uint4*)&dst[off] = cv.u;
        }
    }
}

// ---------------------------------------------------------------------------
// Kernel 2: flash attention — R6 body (verified clean & fastest), NSLICE 8->4
// via NBODY 16->32. ONLY the rolled-loop trip count changes: identical live
// set (~48 AGPR + ~62 VGPR -> 4 waves/SIMD), identical 2-body rotation, perm
// pack, lacc l-sum, scatter epilogue. Grid 1024 = exactly one 4-blocks/CU
// round (no second-round tail); Opart writes halve to 16.8 MB; each key's
// K/V re-read by half as many blocks.
// R3/R4 lesson encoded: their NSLICE=4 failures were register accidents
// (unroll pragma / lacc at 160 regs), not slice-count effects.
// Spill gate: attn WRITE_SIZE > 25 MB next round => revert NBODY to 16.
// ---------------------------------------------------------------------------
__global__ __launch_bounds__(256, 4) void attn_kernel(
    const __bf16* __restrict__ qswz, const __bf16* __restrict__ kswz,
    const __bf16* __restrict__ vswz, __bf16* __restrict__ Opart,
    float* __restrict__ lws)
{
    const int t    = threadIdx.x;
    const int lane = t & 63, w = t >> 6;
    const int l31 = lane & 31, lh = lane >> 5;
    const int bid   = blockIdx.x;
    const int xcd   = bid & 7;
    const int batch = xcd >> 1;              // constant per XCD
    const int spL   = xcd & 1;               // slice bit0, constant per XCD
    const int idx   = bid >> 3;              // 0..127
    const int qpair = idx & 63;              // 0..63
    const int spH   = idx >> 6;              // 0..1
    const int slice = (spH << 1) | spL;      // 0..3 (block-uniform)
    const int qb32  = qpair * 2 + (w >> 1);  // waves pair on q
    const int h     = w & 1;                 // channel half
    const int ks0   = slice * (32 * NBODY);  // first key of this slice

    // Q B-frag, fixed: n = q = 32*qb32 + l31, k = ch = 8*lh + j
    const bf16x8 qf = *(const bf16x8*)
        &qswz[(((size_t)batch * 128 + qb32) * 64 + lane) * 8];

    const __bf16* kptr = kswz + ((size_t)batch * 128 + (ks0 >> 5)) * 512 + lane * 8;
    const __bf16* vptr = vswz + ((size_t)batch * 256 + (ks0 >> 4)) * 2048
                       + h * 1024 + lane * 8;

    f32x16 O0 = zero16(), O1 = zero16();
    float  lacc = 0.f;
    const bool do_l = (h == 0);              // wave-uniform

    // prologue: body 0 K and V, then its scores
    bf16x8 kf = *(const bf16x8*)(kptr);
    bf16x8 va[4], vb[4];
    #pragma unroll
    for (int s = 0; s < 2; ++s) {            // body 0: kb16 = s, cg = 2h+ct
        va[2*s]     = *(const bf16x8*)(vptr + (size_t)(s * 4)     * 512);
        va[2*s + 1] = *(const bf16x8*)(vptr + (size_t)(s * 4 + 1) * 512);
    }
    f32x16 S = MFMA32(kf, qf, zero16());

// Body m (32 keys): S holds scores (computed at end of previous body).
// pk.f[0] = keys [32m,32m+16), pk.f[1] = [32m+16,32m+32) — verified against
// vswz key layout: bf16 j of pk.f[s] = S[8s+j] = key 16s+(j&3)+8*(j>>2)+4lh.
#define ATTN_BODY(M, CUR, NXT)                                                \
    {                                                                         \
        const int mn = ((M) + 1 < NBODY) ? (M) + 1 : (M);                     \
        kf = *(const bf16x8*)(kptr + (size_t)mn * 512);                       \
        _Pragma("unroll")                                                     \
        for (int s = 0; s < 2; ++s) {                                         \
            NXT[2*s]     = *(const bf16x8*)(vptr + (size_t)((2*mn+s)*4  )*512);\
            NXT[2*s + 1] = *(const bf16x8*)(vptr + (size_t)((2*mn+s)*4+1)*512);\
        }                                                                     \
        union { uint32_t u32[8]; bf16x8 f[2]; } pk;                           \
        _Pragma("unroll")                                                     \
        for (int i = 0; i < 8; ++i) {                                         \
            int e0 = (int)fmaf(S[2*i],   128.f, SCH_BIAS);                    \
            int e1 = (int)fmaf(S[2*i+1], 128.f, SCH_BIAS);                    \
            pk.u32[i] = __builtin_amdgcn_perm((uint32_t)e1,                   \
                                              (uint32_t)e0, 0x05040100u);     \
            if (do_l) {                                                       \
                union { uint32_t u; float fv; } c0, c1;                       \
                c0.u = (uint32_t)e0 << 16; c1.u = (uint32_t)e1 << 16;         \
                lacc += c0.fv + c1.fv;                                        \
            }                                                                 \
        }                                                                     \
        O0 = MFMA32(pk.f[0], CUR[0], O0);                                     \
        O1 = MFMA32(pk.f[0], CUR[1], O1);                                     \
        O0 = MFMA32(pk.f[1], CUR[2], O0);                                     \
        O1 = MFMA32(pk.f[1], CUR[3], O1);                                     \
        S = MFMA32(kf, qf, zero16());                                         \
    }

    for (int m = 0; m < NBODY; m += 2) {
        ATTN_BODY(m,     va, vb);
        ATTN_BODY(m + 1, vb, va);
    }
#undef ATTN_BODY

    const long base = (long)batch * NN;

    // ---- l: lane (l31,lh) summed 16 of each body's 32 keys for q = l31;
    //      partner lane (same l31, lh^1) holds the complement.
    float lfull = lacc + __shfl_xor(lacc, 32);
    if (h == 0 && lh == 0)
        lws[(size_t)slice * NROWS + base + qb32 * 32 + l31] = lfull;

    // ---- O partial -> Opart[slice][row][ch] bf16 (col = ch = 64h+32ct+l31) --
    #pragma unroll
    for (int ct = 0; ct < 2; ++ct) {
        f32x16 Ov = ct ? O1 : O0;
        #pragma unroll
        for (int r = 0; r < 16; ++r) {
            int q = qb32 * 32 + (r & 3) + 8 * (r >> 2) + 4 * lh;
            Opart[((size_t)slice * NROWS + base + q) * NC + 64 * h + 32 * ct + l31]
                = (__bf16)Ov[r];
        }
    }
}

// ---------------------------------------------------------------------------
// Kernel 3: combine 4 slice partials + epilogue: out = gamma*(SumO/Suml)+x.
// ---------------------------------------------------------------------------
__global__ __launch_bounds__(256) void combine_kernel(
    const __bf16* __restrict__ Op, const float* __restrict__ lws,
    const float* __restrict__ x, const float* __restrict__ gamma,
    float* __restrict__ out)
{
    __shared__ float gl[32];
    const int  t    = threadIdx.x;
    const long row0 = (long)blockIdx.x * 32;
    if (t < 32) {
        float l = 0.f;
        #pragma unroll
        for (int s = 0; s < NSLICE; ++s) l += lws[(size_t)s * NROWS + row0 + t];
        gl[t] = gamma[0] / l;
    }
    __syncthreads();
    const size_t s1 = (size_t)NROWS * NC;
    #pragma unroll
    for (int i = 0; i < 2; ++i) {
        int idx = t + 256 * i;                 // < 512 uint4 groups
        int r = idx >> 4, c8 = (idx & 15) * 8;
        size_t g = (size_t)(row0 + r) * NC + c8;
        float a[8];
        #pragma unroll
        for (int j = 0; j < 8; ++j) a[j] = 0.f;
        #pragma unroll
        for (int s = 0; s < NSLICE; ++s) {
            union { __bf16 h[8]; uint4 u; } av;
            av.u = *(const uint4*)&Op[s1 * s + g];
            #pragma unroll
            for (int j = 0; j < 8; ++j) a[j] += (float)av.h[j];
        }
        float sc = gl[r];
        float4 x0 = *(const float4*)&x[g];
        float4 x1 = *(const float4*)&x[g + 4];
        float4 o0, o1;
        o0.x = a[0] * sc + x0.x; o0.y = a[1] * sc + x0.y;
        o0.z = a[2] * sc + x0.z; o0.w = a[3] * sc + x0.w;
        o1.x = a[4] * sc + x1.x; o1.y = a[5] * sc + x1.y;
        o1.z = a[6] * sc + x1.z; o1.w = a[7] * sc + x1.w;
        *(float4*)&out[g]     = o0;
        *(float4*)&out[g + 4] = o1;
    }
}

// ---------------------------------------------------------------------------
extern "C" void kernel_launch(void* const* d_in, const int* in_sizes, int n_in,
                              void* d_out, int out_size, void* d_ws, size_t ws_size,
                              hipStream_t stream) {
    const float* x     = (const float*)d_in[0];
    const float* Wb    = (const float*)d_in[1];
    const float* Wc    = (const float*)d_in[2];
    const float* Wd    = (const float*)d_in[3];
    const float* gamma = (const float*)d_in[4];
    float*       out   = (float*)d_out;

    // ws: qswz .5M | kswz .5M | vswz 4M | Opart 4x4M bf16 | lws 256K | Wp 40K
    __bf16* qswz  = (__bf16*)d_ws;
    __bf16* kswz  = qswz + (size_t)NROWS * NCQ;
    __bf16* vswz  = kswz + (size_t)NROWS * NCQ;
    __bf16* Opart = vswz + (size_t)NB * NC * NN;
    float*  lws   = (float*)(Opart + (size_t)NSLICE * NROWS * NC);
    __bf16* Wp    = (__bf16*)(lws + (size_t)NSLICE * NROWS);

    wpre_kernel   <<<80, 256, 0, stream>>>(Wb, Wc, Wd, Wp);
    proj_kernel   <<<NROWS / 32, 256, 0, stream>>>(x, Wp, qswz, kswz, vswz);
    attn_kernel   <<<NB * 64 * NSLICE, 256, 0, stream>>>(qswz, kswz, vswz, Opart, lws);
    combine_kernel<<<NROWS / 32, 256, 0, stream>>>(Opart, lws, x, gamma, out);
}